// Round 1
// baseline (2624.423 us; speedup 1.0000x reference)
//
#include <hip/hip_runtime.h>
#include <math.h>

#define L     2048
#define DM    1024
#define DI    2048
#define NH    8
#define DHD   256
#define DHID  2048

// ---------------- LayerNorm (D = 1024, 256 threads, 4 elems/thread) ----------------
__global__ __launch_bounds__(256) void ln_kernel(const float* __restrict__ x,
    const float* __restrict__ w, float* __restrict__ out, int D) {
  const int row = blockIdx.x;
  const float* xr = x + (size_t)row * D;
  const int i0 = threadIdx.x * 4;
  float4 v4 = *(const float4*)(xr + i0);
  float s  = v4.x + v4.y + v4.z + v4.w;
  float s2 = v4.x*v4.x + v4.y*v4.y + v4.z*v4.z + v4.w*v4.w;
#pragma unroll
  for (int off = 32; off; off >>= 1) { s += __shfl_xor(s, off); s2 += __shfl_xor(s2, off); }
  __shared__ float rs[4], rs2[4];
  if ((threadIdx.x & 63) == 0) { rs[threadIdx.x >> 6] = s; rs2[threadIdx.x >> 6] = s2; }
  __syncthreads();
  s  = rs[0] + rs[1] + rs[2] + rs[3];
  s2 = rs2[0] + rs2[1] + rs2[2] + rs2[3];
  const float mean = s / D;
  const float inv = rsqrtf(s2 / D - mean * mean + 1e-5f);
  float4 w4 = *(const float4*)(w + i0);
  float4 o;
  o.x = (v4.x - mean) * inv * w4.x;
  o.y = (v4.y - mean) * inv * w4.y;
  o.z = (v4.z - mean) * inv * w4.z;
  o.w = (v4.w - mean) * inv * w4.w;
  *(float4*)(out + (size_t)row * D + i0) = o;
}

// ---------------- f32 GEMM, C[M,N] = A[M,K] @ B[N,K]^T (+bias, +resid) --------------
// 128x128 tile, BK=8, 256 threads, 8x8 per thread. M,N multiples of 128, K of 8.
template<bool BIAS, bool RESID>
__global__ __launch_bounds__(256) void gemm_nt(const float* __restrict__ A,
    const float* __restrict__ B, const float* __restrict__ bias,
    const float* __restrict__ resid, float* __restrict__ C, int M, int N, int K) {
  __shared__ __align__(16) float As[8][132];
  __shared__ __align__(16) float Bs[8][132];
  const int tid = threadIdx.x;
  const int tx = tid & 15, ty = tid >> 4;
  const int arow = tid >> 1, akq = (tid & 1) * 4;
  const float* Ap = A + (size_t)(blockIdx.y * 128 + arow) * K + akq;
  const float* Bp = B + (size_t)(blockIdx.x * 128 + arow) * K + akq;
  float acc[8][8] = {};
  for (int k0 = 0; k0 < K; k0 += 8) {
    float4 av = *(const float4*)(Ap + k0);
    float4 bv = *(const float4*)(Bp + k0);
    __syncthreads();
    As[akq+0][arow]=av.x; As[akq+1][arow]=av.y; As[akq+2][arow]=av.z; As[akq+3][arow]=av.w;
    Bs[akq+0][arow]=bv.x; Bs[akq+1][arow]=bv.y; Bs[akq+2][arow]=bv.z; Bs[akq+3][arow]=bv.w;
    __syncthreads();
#pragma unroll
    for (int kk = 0; kk < 8; ++kk) {
      float a[8], b[8];
      *(float4*)(a)   = *(const float4*)&As[kk][ty*8];
      *(float4*)(a+4) = *(const float4*)&As[kk][ty*8+4];
      *(float4*)(b)   = *(const float4*)&Bs[kk][tx*8];
      *(float4*)(b+4) = *(const float4*)&Bs[kk][tx*8+4];
#pragma unroll
      for (int i = 0; i < 8; ++i)
#pragma unroll
        for (int j = 0; j < 8; ++j) acc[i][j] = fmaf(a[i], b[j], acc[i][j]);
    }
  }
  const int cn = blockIdx.x * 128 + tx * 8;
#pragma unroll
  for (int i = 0; i < 8; ++i) {
    const size_t r = blockIdx.y * 128 + ty * 8 + i;
    float o[8];
#pragma unroll
    for (int j = 0; j < 8; ++j) {
      float vv = acc[i][j];
      if (BIAS)  vv += bias[cn + j];
      if (RESID) vv += resid[r * N + cn + j];
      o[j] = vv;
    }
    *(float4*)(C + r * N + cn)     = *(float4*)(o);
    *(float4*)(C + r * N + cn + 4) = *(float4*)(o + 4);
  }
}

// ---------------- f32 GEMM NN batched over z: C = A[M,K] @ B[K,N] -------------------
// A offset z*aZ (column offset into row-major lda matrix), B offset z*bZ, C offset z*cZ.
__global__ __launch_bounds__(256) void gemm_nn_b(const float* __restrict__ A, int aZ, int lda,
    const float* __restrict__ B, int bZ, int ldb,
    float* __restrict__ C, int cZ, int ldc, int M, int N, int K) {
  const float* Ab = A + (size_t)blockIdx.z * aZ;
  const float* Bb = B + (size_t)blockIdx.z * bZ;
  float* Cb = C + (size_t)blockIdx.z * cZ;
  __shared__ __align__(16) float As[8][132];
  __shared__ __align__(16) float Bs[8][132];
  const int tid = threadIdx.x;
  const int tx = tid & 15, ty = tid >> 4;
  const int arow = tid >> 1, akq = (tid & 1) * 4;
  const int bkk = tid >> 5, bn4 = (tid & 31) * 4;
  const float* Ap = Ab + (size_t)(blockIdx.y * 128 + arow) * lda + akq;
  const float* Bp = Bb + (size_t)bkk * ldb + blockIdx.x * 128 + bn4;
  float acc[8][8] = {};
  for (int k0 = 0; k0 < K; k0 += 8) {
    float4 av = *(const float4*)(Ap + k0);
    float4 bv = *(const float4*)(Bp + (size_t)k0 * ldb);
    __syncthreads();
    As[akq+0][arow]=av.x; As[akq+1][arow]=av.y; As[akq+2][arow]=av.z; As[akq+3][arow]=av.w;
    *(float4*)&Bs[bkk][bn4] = bv;
    __syncthreads();
#pragma unroll
    for (int kk = 0; kk < 8; ++kk) {
      float a[8], b[8];
      *(float4*)(a)   = *(const float4*)&As[kk][ty*8];
      *(float4*)(a+4) = *(const float4*)&As[kk][ty*8+4];
      *(float4*)(b)   = *(const float4*)&Bs[kk][tx*8];
      *(float4*)(b+4) = *(const float4*)&Bs[kk][tx*8+4];
#pragma unroll
      for (int i = 0; i < 8; ++i)
#pragma unroll
        for (int j = 0; j < 8; ++j) acc[i][j] = fmaf(a[i], b[j], acc[i][j]);
    }
  }
  const int cn = blockIdx.x * 128 + tx * 8;
#pragma unroll
  for (int i = 0; i < 8; ++i) {
    const size_t r = blockIdx.y * 128 + ty * 8 + i;
    *(float4*)(Cb + r * ldc + cn)     = *(float4*)(acc[i]);
    *(float4*)(Cb + r * ldc + cn + 4) = *(float4*)(acc[i] + 4);
  }
}

// ---------------- causal conv (width 4) + silu ----------------
__global__ void conv_silu_kernel(const float* __restrict__ proj, const float* __restrict__ ck,
    const float* __restrict__ cb, float* __restrict__ xc) {
  const int idx = blockIdx.x * 256 + threadIdx.x;   // over L*DI
  const int l = idx >> 11, c = idx & (DI - 1);
  float s = cb[c];
#pragma unroll
  for (int t = 0; t < 4; ++t) {
    const int lm = l - t;
    if (lm >= 0) s = fmaf(ck[c * 4 + t], proj[(size_t)lm * (2 * DI) + c], s);
  }
  xc[idx] = s / (1.f + expf(-s));
}

// ---------------- gates: ig/fg = concat(q,k,v) @ w.T + b, stored [head][l] ----------
__global__ __launch_bounds__(256) void gates_kernel(const float* __restrict__ q,
    const float* __restrict__ k, const float* __restrict__ v,
    const float* __restrict__ igw, const float* __restrict__ igb,
    const float* __restrict__ fgw, const float* __restrict__ fgb,
    float* __restrict__ ig_t, float* __restrict__ fg_t) {
  const int l = blockIdx.x;
  const size_t ro = (size_t)l * DI;
  __shared__ float red[4];
  for (int o = 0; o < 16; ++o) {
    const int n = o & 7;
    const bool isF = (o >= 8);
    const float* w = (isF ? fgw : igw) + (size_t)n * (3 * DI);
    float s = 0.f;
    for (int c = threadIdx.x * 4; c < DI; c += 1024) {
      float4 qv = *(const float4*)(q + ro + c);
      float4 w0 = *(const float4*)(w + c);
      float4 kv = *(const float4*)(k + ro + c);
      float4 w1 = *(const float4*)(w + DI + c);
      float4 vv = *(const float4*)(v + ro + c);
      float4 w2 = *(const float4*)(w + 2 * DI + c);
      s += qv.x*w0.x + qv.y*w0.y + qv.z*w0.z + qv.w*w0.w;
      s += kv.x*w1.x + kv.y*w1.y + kv.z*w1.z + kv.w*w1.w;
      s += vv.x*w2.x + vv.y*w2.y + vv.z*w2.z + vv.w*w2.w;
    }
#pragma unroll
    for (int off = 32; off; off >>= 1) s += __shfl_xor(s, off);
    if ((threadIdx.x & 63) == 0) red[threadIdx.x >> 6] = s;
    __syncthreads();
    if (threadIdx.x == 0) {
      float tot = red[0] + red[1] + red[2] + red[3] + (isF ? fgb[n] : igb[n]);
      (isF ? fg_t : ig_t)[(size_t)n * L + l] = tot;
    }
    __syncthreads();
  }
}

// ---------------- per-head scan: e=cumsum(logsig(fg)), w=ig-e, M=prefmax(w) ---------
__global__ __launch_bounds__(256) void scan_kernel(const float* __restrict__ ig_t,
    const float* __restrict__ fg_t, float* __restrict__ e_b, float* __restrict__ M_b,
    float* __restrict__ wv_b) {
  const int n = blockIdx.x;
  __shared__ float lf[L];
  for (int i = threadIdx.x; i < L; i += 256) {
    float xg = fg_t[(size_t)n * L + i];
    lf[i] = (xg >= 0.f) ? -log1pf(expf(-xg)) : (xg - log1pf(expf(xg)));
  }
  __syncthreads();
  if (threadIdx.x == 0) {
    float run = 0.f, mx = -3.4e38f;
    for (int i = 0; i < L; ++i) {
      run += lf[i];
      const float w = ig_t[(size_t)n * L + i] - run;
      mx = fmaxf(mx, w);
      e_b[(size_t)n * L + i] = run;
      M_b[(size_t)n * L + i] = mx;
      wv_b[(size_t)n * L + i] = w;
    }
  }
}

// ---------------- fused mLSTM attention: one (head, 32-row q-tile) per block --------
__global__ __launch_bounds__(256) void mlstm_attn(const float* __restrict__ q,
    const float* __restrict__ k, const float* __restrict__ v,
    const float* __restrict__ e_b, const float* __restrict__ M_b,
    const float* __restrict__ wv_b, float* __restrict__ hflat) {
  const int n = blockIdx.y;
  const int q0 = blockIdx.x * 32;
  const int tid = threadIdx.x;
  __shared__ __align__(16) float Qs[32][260];
  __shared__ __align__(16) float Ks[32][260];
  __shared__ __align__(16) float Vs[32][260];
  __shared__ float Cs[32][33];
  __shared__ float Ml_s[32], el_s[32], Snorm[32], wvs[32];

  const int lr = tid >> 3, cg = tid & 7;     // load mapping: 32 rows x 8 col-groups
  {
    const float* src = q + (size_t)(q0 + lr) * DI + n * DHD + cg * 4;
#pragma unroll
    for (int cc = 0; cc < 8; ++cc) {
      float4 v4 = *(const float4*)(src + cc * 32);
      v4.x *= 0.0625f; v4.y *= 0.0625f; v4.z *= 0.0625f; v4.w *= 0.0625f;
      *(float4*)&Qs[lr][cg * 4 + cc * 32] = v4;
    }
    if (tid < 32) { Ml_s[tid] = M_b[(size_t)n * L + q0 + tid];
                    el_s[tid] = e_b[(size_t)n * L + q0 + tid]; }
  }

  float4 O[8];
#pragma unroll
  for (int cch = 0; cch < 8; ++cch) O[cch] = make_float4(0.f, 0.f, 0.f, 0.f);
  float rowsum = 0.f;

  const int i_pv = tid >> 3, dg = tid & 7;   // PV mapping
  const int ti = tid >> 4, tj = tid & 15;    // scores mapping (2x2 each)
  const int i0 = ti * 2, j0 = tj * 2;

  for (int m0 = 0; m0 <= q0 + 31; m0 += 32) {
    __syncthreads();
    {
      const float* ksrc = k + (size_t)(m0 + lr) * DI + n * DHD + cg * 4;
      const float* vsrc = v + (size_t)(m0 + lr) * DI + n * DHD + cg * 4;
#pragma unroll
      for (int cc = 0; cc < 8; ++cc) {
        *(float4*)&Ks[lr][cg * 4 + cc * 32] = *(const float4*)(ksrc + cc * 32);
        *(float4*)&Vs[lr][cg * 4 + cc * 32] = *(const float4*)(vsrc + cc * 32);
      }
      if (tid < 32) wvs[tid] = wv_b[(size_t)n * L + m0 + tid];
    }
    __syncthreads();
    float a00 = 0.f, a01 = 0.f, a10 = 0.f, a11 = 0.f;
#pragma unroll 4
    for (int t = 0; t < DHD; t += 4) {
      float4 qa = *(const float4*)&Qs[i0][t];
      float4 qb = *(const float4*)&Qs[i0 + 1][t];
      float4 ka = *(const float4*)&Ks[j0][t];
      float4 kb = *(const float4*)&Ks[j0 + 1][t];
      a00 += qa.x*ka.x + qa.y*ka.y + qa.z*ka.z + qa.w*ka.w;
      a01 += qa.x*kb.x + qa.y*kb.y + qa.z*kb.z + qa.w*kb.w;
      a10 += qb.x*ka.x + qb.y*ka.y + qb.z*ka.z + qb.w*ka.w;
      a11 += qb.x*kb.x + qb.y*kb.y + qb.z*kb.z + qb.w*kb.w;
    }
    {
      const float m0f = Ml_s[i0], m1f = Ml_s[i0 + 1];
      const int gi0 = q0 + i0, gi1 = gi0 + 1, gj0 = m0 + j0, gj1 = gj0 + 1;
      const float w0 = wvs[j0], w1 = wvs[j0 + 1];
      Cs[i0][j0]       = (gj0 <= gi0) ? a00 * expf(w0 - m0f) : 0.f;
      Cs[i0][j0 + 1]   = (gj1 <= gi0) ? a01 * expf(w1 - m0f) : 0.f;
      Cs[i0 + 1][j0]   = (gj0 <= gi1) ? a10 * expf(w0 - m1f) : 0.f;
      Cs[i0 + 1][j0+1] = (gj1 <= gi1) ? a11 * expf(w1 - m1f) : 0.f;
    }
    __syncthreads();
#pragma unroll 4
    for (int j = 0; j < 32; ++j) {
      const float cv = Cs[i_pv][j];
      rowsum += cv;
#pragma unroll
      for (int cch = 0; cch < 8; ++cch) {
        float4 vv = *(const float4*)&Vs[j][dg * 4 + cch * 32];
        O[cch].x = fmaf(cv, vv.x, O[cch].x);
        O[cch].y = fmaf(cv, vv.y, O[cch].y);
        O[cch].z = fmaf(cv, vv.z, O[cch].z);
        O[cch].w = fmaf(cv, vv.w, O[cch].w);
      }
    }
  }
  if (dg == 0) Snorm[i_pv] = rowsum;
  __syncthreads();
  {
    const float Sv = Snorm[i_pv];
    const float floorv = expf(-(el_s[i_pv] + Ml_s[i_pv]));
    const float sc = 1.f / (fmaxf(fabsf(Sv), floorv) + 1e-6f);
    float* dst = hflat + (size_t)(q0 + i_pv) * DI + n * DHD + dg * 4;
#pragma unroll
    for (int cch = 0; cch < 8; ++cch) {
      float4 o = O[cch];
      o.x *= sc; o.y *= sc; o.z *= sc; o.w *= sc;
      *(float4*)(dst + cch * 32) = o;
    }
  }
}

// ---------------- GroupNorm + skip*xc, then * silu(res) → y -------------------------
__global__ __launch_bounds__(64) void gn_y_kernel(const float* __restrict__ hflat,
    const float* __restrict__ xc, const float* __restrict__ proj,
    const float* __restrict__ gnw, const float* __restrict__ gnb,
    const float* __restrict__ skip, float* __restrict__ y) {
  const int n = blockIdx.x, l = blockIdx.y, lane = threadIdx.x;
  const float* hr = hflat + (size_t)l * DI + n * DHD;
  float vals[4]; float s = 0.f, s2 = 0.f;
#pragma unroll
  for (int u = 0; u < 4; ++u) {
    float t = hr[lane + u * 64]; vals[u] = t; s += t; s2 += t * t;
  }
#pragma unroll
  for (int off = 32; off; off >>= 1) { s += __shfl_xor(s, off); s2 += __shfl_xor(s2, off); }
  const float mean = s * (1.f / DHD);
  const float inv = rsqrtf(s2 * (1.f / DHD) - mean * mean + 1e-5f);
#pragma unroll
  for (int u = 0; u < 4; ++u) {
    const int c = n * DHD + lane + u * 64;
    const float hn = (vals[u] - mean) * inv;
    const float h2 = hn * gnw[c] + gnb[c] + skip[c] * xc[(size_t)l * DI + c];
    const float r = proj[(size_t)l * (2 * DI) + DI + c];
    y[(size_t)l * DI + c] = h2 * (r / (1.f + expf(-r)));
  }
}

// ---------------- gelu(a) * z ----------------
__global__ void gelu_mul_kernel(const float* __restrict__ p, float* __restrict__ g) {
  const int idx = blockIdx.x * 256 + threadIdx.x;   // over L*DHID
  const int l = idx >> 11, c = idx & (DHID - 1);
  const float a = p[(size_t)l * (2 * DHID) + c];
  const float z = p[(size_t)l * (2 * DHID) + DHID + c];
  const float t = 0.7978845608028654f * (a + 0.044715f * a * a * a);
  g[idx] = 0.5f * a * (1.f + tanhf(t)) * z;
}

extern "C" void kernel_launch(void* const* d_in, const int* in_sizes, int n_in,
                              void* d_out, int out_size, void* d_ws, size_t ws_size,
                              hipStream_t stream) {
  const float* x     = (const float*)d_in[0];
  // d_in[1] = mask (tril, constant) — not needed
  const float* ln1w  = (const float*)d_in[2];
  const float* winw  = (const float*)d_in[3];
  const float* winb  = (const float*)d_in[4];
  const float* woutw = (const float*)d_in[5];
  const float* ck    = (const float*)d_in[6];
  const float* cb    = (const float*)d_in[7];
  const float* wq    = (const float*)d_in[8];
  const float* wk    = (const float*)d_in[9];
  const float* wvw   = (const float*)d_in[10];
  const float* igw   = (const float*)d_in[11];
  const float* igb   = (const float*)d_in[12];
  const float* fgw   = (const float*)d_in[13];
  const float* fgb   = (const float*)d_in[14];
  const float* gnw   = (const float*)d_in[15];
  const float* gnb   = (const float*)d_in[16];
  const float* skip  = (const float*)d_in[17];
  const float* ln2w  = (const float*)d_in[18];
  const float* fwin  = (const float*)d_in[19];
  const float* fwout = (const float*)d_in[20];
  float* out = (float*)d_out;
  float* ws = (float*)d_ws;

  const size_t MEG = 1u << 20;
  float* h     = ws;               // 2M floats
  float* proj  = ws + 2 * MEG;     // 8M
  float* xc    = ws + 10 * MEG;    // 4M
  float* q     = ws + 14 * MEG;    // 4M
  float* kbuf  = ws + 18 * MEG;    // 4M
  float* vbuf  = ws + 22 * MEG;    // 4M
  float* ig_t  = ws + 26 * MEG;    // 16K
  float* fg_t  = ig_t + NH * L;
  float* e_b   = fg_t + NH * L;
  float* M_b   = e_b + NH * L;
  float* wv_b  = M_b + NH * L;
  float* hflat = ws + 27 * MEG;    // 4M
  float* y     = q;                // reuse (q dead after attention)
  float* x2    = kbuf;             // reuse (k dead after attention)
  float* p     = proj;             // reuse (proj dead after gn_y)
  float* g     = xc;               // reuse (xc dead after gn_y)

  // 1. h = LN(x)
  ln_kernel<<<L, 256, 0, stream>>>(x, ln1w, h, DM);
  // 2. proj = h @ win_w.T + win_b
  gemm_nt<true, false><<<dim3(4096 / 128, L / 128), 256, 0, stream>>>(
      h, winw, winb, nullptr, proj, L, 4096, DM);
  // 3. xc = silu(causal_conv(xi))
  conv_silu_kernel<<<(L * DI) / 256, 256, 0, stream>>>(proj, ck, cb, xc);
  // 4. q,k,v head-diagonal projections
  gemm_nn_b<<<dim3(2, L / 128, NH), 256, 0, stream>>>(xc, DHD, DI, wq, DHD * DHD, DHD,
                                                      q, DHD, DI, L, DHD, DHD);
  gemm_nn_b<<<dim3(2, L / 128, NH), 256, 0, stream>>>(xc, DHD, DI, wk, DHD * DHD, DHD,
                                                      kbuf, DHD, DI, L, DHD, DHD);
  gemm_nn_b<<<dim3(2, L / 128, NH), 256, 0, stream>>>(proj, DHD, 2 * DI, wvw, DHD * DHD, DHD,
                                                      vbuf, DHD, DI, L, DHD, DHD);
  // 5. gates
  gates_kernel<<<L, 256, 0, stream>>>(q, kbuf, vbuf, igw, igb, fgw, fgb, ig_t, fg_t);
  // 6. per-head scan
  scan_kernel<<<NH, 256, 0, stream>>>(ig_t, fg_t, e_b, M_b, wv_b);
  // 7. fused mLSTM
  mlstm_attn<<<dim3(L / 32, NH), 256, 0, stream>>>(q, kbuf, vbuf, e_b, M_b, wv_b, hflat);
  // 8. y = (GN(hflat) + skip*xc) * silu(res)
  gn_y_kernel<<<dim3(NH, L), 64, 0, stream>>>(hflat, xc, proj, gnw, gnb, skip, y);
  // 9. x2 = x + y @ wout_w.T
  gemm_nt<false, true><<<dim3(DM / 128, L / 128), 256, 0, stream>>>(
      y, woutw, nullptr, x, x2, L, DM, DI);
  // 10. hf = LN(x2)  (reuse h)
  ln_kernel<<<L, 256, 0, stream>>>(x2, ln2w, h, DM);
  // 11. p = hf @ ffn_win_w.T
  gemm_nt<false, false><<<dim3(4096 / 128, L / 128), 256, 0, stream>>>(
      h, fwin, nullptr, nullptr, p, L, 4096, DM);
  // 12. g = gelu(a) * z
  gelu_mul_kernel<<<(L * DHID) / 256, 256, 0, stream>>>(p, g);
  // 13. out = x2 + g @ ffn_wout_w.T
  gemm_nt<false, true><<<dim3(DM / 128, L / 128), 256, 0, stream>>>(
      g, fwout, nullptr, x2, out, L, DM, DHID);
}

// Round 2
// 590.240 us; speedup vs baseline: 4.4464x; 4.4464x over previous
//
#include <hip/hip_runtime.h>
#include <math.h>

#define L     2048
#define DM    1024
#define DI    2048
#define NH    8
#define DHD   256
#define DHID  2048

typedef short bf16x8 __attribute__((ext_vector_type(8)));
typedef float f32x4  __attribute__((ext_vector_type(4)));

__device__ inline float b2f(ushort h) {
  unsigned u = ((unsigned)h) << 16;
  return __builtin_bit_cast(float, u);
}
__device__ inline ushort f2b(float f) {
  unsigned u = __builtin_bit_cast(unsigned, f);
  unsigned r = (u + 0x7FFFu + ((u >> 16) & 1u)) >> 16;
  return (ushort)r;
}
__device__ inline unsigned pk2(ushort lo, ushort hi) { return (unsigned)lo | ((unsigned)hi << 16); }

// Read one bf16 A/B fragment (8 bf16) from a swizzled row-major LDS tile.
// Tile rows are rowBytes long; swizzle: 16B-block index ^= (row&7).
// byte0 = in-row byte offset of k-piece0 (piece1 at +32B).
__device__ inline bf16x8 frag_ld(const ushort* tile, int rowBytes, int row, int byte0) {
  const char* bp = (const char*)tile + row * rowBytes;
  const int sw = (row & 7) << 4;
  const int b1 = byte0 + 32;
  bf16x8 r;
  *(unsigned long long*)&r =
      *(const unsigned long long*)(bp + (((byte0 & ~15) ^ sw) | (byte0 & 15)));
  *((unsigned long long*)&r + 1) =
      *(const unsigned long long*)(bp + (((b1 & ~15) ^ sw) | (b1 & 15)));
  return r;
}

// ---------------- f32 -> bf16 cast ----------------
__global__ __launch_bounds__(256) void cast_kernel(const float* __restrict__ src,
    ushort* __restrict__ dst, int n) {
  const int i = (blockIdx.x * 256 + threadIdx.x) * 8;
  if (i >= n) return;
  float4 a = *(const float4*)(src + i);
  float4 b = *(const float4*)(src + i + 4);
  uint4 o;
  o.x = pk2(f2b(a.x), f2b(a.y));
  o.y = pk2(f2b(a.z), f2b(a.w));
  o.z = pk2(f2b(b.x), f2b(b.y));
  o.w = pk2(f2b(b.z), f2b(b.w));
  *(uint4*)(dst + i) = o;
}

// ---------------- per-head W[c][d] -> Wt[d][c] bf16 ----------------
__global__ __launch_bounds__(256) void wtrans_kernel(const float* __restrict__ wq,
    const float* __restrict__ wk, const float* __restrict__ wv, ushort* __restrict__ out) {
  const int z = blockIdx.z;          // mat*8 + head
  const int mat = z >> 3, h = z & 7;
  const float* src = (mat == 0 ? wq : (mat == 1 ? wk : wv)) + (size_t)h * 65536;
  ushort* dst = out + (size_t)z * 65536;
  __shared__ float s[32][33];
  const int r = threadIdx.x >> 5, c = threadIdx.x & 31;
  const int I0 = blockIdx.y * 32, J0 = blockIdx.x * 32;
#pragma unroll
  for (int k = 0; k < 4; ++k) s[r + 8 * k][c] = src[(size_t)(I0 + r + 8 * k) * 256 + J0 + c];
  __syncthreads();
#pragma unroll
  for (int k = 0; k < 4; ++k)
    dst[(size_t)(J0 + r + 8 * k) * 256 + I0 + c] = f2b(s[c][r + 8 * k]);
}

// ---------------- LayerNorm -> bf16 ----------------
__global__ __launch_bounds__(256) void ln_kernel(const float* __restrict__ x,
    const float* __restrict__ w, ushort* __restrict__ out, int D) {
  const int row = blockIdx.x;
  const float* xr = x + (size_t)row * D;
  const int i0 = threadIdx.x * 4;
  float4 v4 = *(const float4*)(xr + i0);
  float s  = v4.x + v4.y + v4.z + v4.w;
  float s2 = v4.x*v4.x + v4.y*v4.y + v4.z*v4.z + v4.w*v4.w;
#pragma unroll
  for (int off = 32; off; off >>= 1) { s += __shfl_xor(s, off); s2 += __shfl_xor(s2, off); }
  __shared__ float rs[4], rs2[4];
  if ((threadIdx.x & 63) == 0) { rs[threadIdx.x >> 6] = s; rs2[threadIdx.x >> 6] = s2; }
  __syncthreads();
  s  = rs[0] + rs[1] + rs[2] + rs[3];
  s2 = rs2[0] + rs2[1] + rs2[2] + rs2[3];
  const float mean = s / D;
  const float inv = rsqrtf(s2 / D - mean * mean + 1e-5f);
  float4 w4 = *(const float4*)(w + i0);
  ushort4 o4 = make_ushort4(
      f2b((v4.x - mean) * inv * w4.x), f2b((v4.y - mean) * inv * w4.y),
      f2b((v4.z - mean) * inv * w4.z), f2b((v4.w - mean) * inv * w4.w));
  *(ushort4*)(out + (size_t)row * D + i0) = o4;
}

// ---------------- bf16 MFMA GEMM: C[M,N] = A[M,K] @ B[N,K]^T ----------------
// 128x128 tile, BK=64, 256 threads (4 waves, 2x2 quadrants of 64x64).
template<bool BIAS, bool RESID, bool F32OUT, bool BF16OUT>
__global__ __launch_bounds__(256) void gemm_bf16(
    const ushort* __restrict__ A, int lda, long aBat,
    const ushort* __restrict__ B, int ldb, long bBat,
    const float* __restrict__ bias,
    const float* __restrict__ resid, int ldr,
    float* __restrict__ Cf, int ldc,
    ushort* __restrict__ Cb, int ldcb, int cbLim, long cBat,
    int K) {
  __shared__ ushort As[128 * 64];
  __shared__ ushort Bs[128 * 64];
  const int tid = threadIdx.x;
  const int w = tid >> 6, lane = tid & 63;
  const int g = lane >> 4, li = lane & 15;
  const int wr = (w >> 1) * 64, wc = (w & 1) * 64;
  const int row0 = blockIdx.y * 128, col0 = blockIdx.x * 128;
  const ushort* Ab = A + (size_t)blockIdx.z * aBat;
  const ushort* Bb = B + (size_t)blockIdx.z * bBat;

  f32x4 acc[4][4];
#pragma unroll
  for (int i = 0; i < 4; ++i)
#pragma unroll
    for (int j = 0; j < 4; ++j) acc[i][j] = (f32x4){0.f, 0.f, 0.f, 0.f};

  const int sr = tid >> 3;        // 0..31 base row
  const int sb = tid & 7;         // 16B block
  const ushort* Ag = Ab + (size_t)(row0 + sr) * lda + sb * 8;
  const ushort* Bg = Bb + (size_t)(col0 + sr) * ldb + sb * 8;

  for (int k0 = 0; k0 < K; k0 += 64) {
    __syncthreads();
#pragma unroll
    for (int i = 0; i < 4; ++i) {
      const int r = sr + 32 * i;
      uint4 va = *(const uint4*)(Ag + (size_t)(32 * i) * lda + k0);
      uint4 vb = *(const uint4*)(Bg + (size_t)(32 * i) * ldb + k0);
      const int off = r * 128 + (((sb ^ (r & 7))) << 4);
      *(uint4*)((char*)As + off) = va;
      *(uint4*)((char*)Bs + off) = vb;
    }
    __syncthreads();
#pragma unroll
    for (int ks = 0; ks < 2; ++ks) {
      bf16x8 af[4], bfr[4];
      const int byte0 = ks * 64 + 8 * g;
#pragma unroll
      for (int rb = 0; rb < 4; ++rb) af[rb] = frag_ld(As, 128, wr + rb * 16 + li, byte0);
#pragma unroll
      for (int cb = 0; cb < 4; ++cb) bfr[cb] = frag_ld(Bs, 128, wc + cb * 16 + li, byte0);
#pragma unroll
      for (int rb = 0; rb < 4; ++rb)
#pragma unroll
        for (int cb = 0; cb < 4; ++cb)
          acc[rb][cb] = __builtin_amdgcn_mfma_f32_16x16x32_bf16(af[rb], bfr[cb], acc[rb][cb], 0, 0, 0);
    }
  }

  // epilogue
#pragma unroll
  for (int rb = 0; rb < 4; ++rb)
#pragma unroll
    for (int cb = 0; cb < 4; ++cb)
#pragma unroll
      for (int j = 0; j < 4; ++j) {
        const int r = row0 + wr + rb * 16 + 4 * g + j;
        const int c = col0 + wc + cb * 16 + li;
        float v = acc[rb][cb][j];
        if (BIAS)  v += bias[c];
        if (RESID) v += resid[(size_t)r * ldr + c];
        if (F32OUT) Cf[(size_t)r * ldc + c] = v;
        if (BF16OUT) {
          if (c < cbLim) Cb[(size_t)blockIdx.z * cBat + (size_t)r * ldcb + c] = f2b(v);
        }
      }
}

// ---------------- causal conv (width 4) + silu -> bf16 ----------------
__global__ __launch_bounds__(256) void conv_silu_kernel(const float* __restrict__ proj,
    const float* __restrict__ ck, const float* __restrict__ cb, ushort* __restrict__ xcb) {
  const int idx = blockIdx.x * 256 + threadIdx.x;   // over L*512
  const int l = idx >> 9, c4 = (idx & 511) * 4;
  float4 s = *(const float4*)(cb + c4);
#pragma unroll
  for (int t = 0; t < 4; ++t) {
    const int lm = l - t;
    if (lm >= 0) {
      float4 pv = *(const float4*)(proj + (size_t)lm * 4096 + c4);
      s.x = fmaf(ck[(c4 + 0) * 4 + t], pv.x, s.x);
      s.y = fmaf(ck[(c4 + 1) * 4 + t], pv.y, s.y);
      s.z = fmaf(ck[(c4 + 2) * 4 + t], pv.z, s.z);
      s.w = fmaf(ck[(c4 + 3) * 4 + t], pv.w, s.w);
    }
  }
  ushort4 o = make_ushort4(f2b(s.x / (1.f + __expf(-s.x))), f2b(s.y / (1.f + __expf(-s.y))),
                           f2b(s.z / (1.f + __expf(-s.z))), f2b(s.w / (1.f + __expf(-s.w))));
  *(ushort4*)(xcb + (size_t)l * 2048 + c4) = o;
}

// ---------------- gates from contiguous qkv3 (bf16) ----------------
__global__ __launch_bounds__(256) void gates_kernel(const ushort* __restrict__ qkv3,
    const ushort* __restrict__ gw, const float* __restrict__ igb, const float* __restrict__ fgb,
    float* __restrict__ ig_t, float* __restrict__ fg_t) {
  const int l = blockIdx.x;
  const ushort* row = qkv3 + (size_t)l * 6144;
  __shared__ float red[4];
  float rf[24];
#pragma unroll
  for (int ch = 0; ch < 3; ++ch) {
    uint4 u = *(const uint4*)(row + (threadIdx.x + 256 * ch) * 8);
    rf[ch*8+0] = b2f((ushort)u.x); rf[ch*8+1] = b2f((ushort)(u.x >> 16));
    rf[ch*8+2] = b2f((ushort)u.y); rf[ch*8+3] = b2f((ushort)(u.y >> 16));
    rf[ch*8+4] = b2f((ushort)u.z); rf[ch*8+5] = b2f((ushort)(u.z >> 16));
    rf[ch*8+6] = b2f((ushort)u.w); rf[ch*8+7] = b2f((ushort)(u.w >> 16));
  }
  for (int o = 0; o < 16; ++o) {
    const ushort* wr_ = gw + (size_t)o * 6144;
    float s = 0.f;
#pragma unroll
    for (int ch = 0; ch < 3; ++ch) {
      uint4 u = *(const uint4*)(wr_ + (threadIdx.x + 256 * ch) * 8);
      s += rf[ch*8+0] * b2f((ushort)u.x) + rf[ch*8+1] * b2f((ushort)(u.x >> 16));
      s += rf[ch*8+2] * b2f((ushort)u.y) + rf[ch*8+3] * b2f((ushort)(u.y >> 16));
      s += rf[ch*8+4] * b2f((ushort)u.z) + rf[ch*8+5] * b2f((ushort)(u.z >> 16));
      s += rf[ch*8+6] * b2f((ushort)u.w) + rf[ch*8+7] * b2f((ushort)(u.w >> 16));
    }
#pragma unroll
    for (int off = 32; off; off >>= 1) s += __shfl_xor(s, off);
    if ((threadIdx.x & 63) == 0) red[threadIdx.x >> 6] = s;
    __syncthreads();
    if (threadIdx.x == 0) {
      const int n = o & 7;
      float tot = red[0] + red[1] + red[2] + red[3] + ((o >= 8) ? fgb[n] : igb[n]);
      ((o >= 8) ? fg_t : ig_t)[(size_t)n * L + l] = tot;
    }
    __syncthreads();
  }
}

// ---------------- per-head scan (parallel) ----------------
__global__ __launch_bounds__(256) void scan_kernel(const float* __restrict__ ig_t,
    const float* __restrict__ fg_t, float* __restrict__ e_b, float* __restrict__ M_b,
    float* __restrict__ wv_b) {
  const int n = blockIdx.x, t = threadIdx.x;
  const int base = n * L + t * 8;
  __shared__ float ps[256], pm[256];
  float lc[8];
  float run = 0.f;
#pragma unroll
  for (int j = 0; j < 8; ++j) {
    float xg = fg_t[base + j];
    float ls = (xg >= 0.f) ? -log1pf(expf(-xg)) : (xg - log1pf(expf(xg)));
    run += ls; lc[j] = run;
  }
  ps[t] = run;
  __syncthreads();
  if (t == 0) { float r = 0.f; for (int i = 0; i < 256; ++i) { float v = ps[i]; ps[i] = r; r += v; } }
  __syncthreads();
  const float eoff = ps[t];
  float wl[8]; float rm = -3.4e38f;
#pragma unroll
  for (int j = 0; j < 8; ++j) {
    float e = eoff + lc[j];
    float wv = ig_t[base + j] - e;
    e_b[base + j] = e; wv_b[base + j] = wv;
    rm = fmaxf(rm, wv); wl[j] = rm;
  }
  pm[t] = rm;
  __syncthreads();
  if (t == 0) { float r = -3.4e38f; for (int i = 0; i < 256; ++i) { float v = pm[i]; pm[i] = r; r = fmaxf(r, v); } }
  __syncthreads();
  const float moff = pm[t];
#pragma unroll
  for (int j = 0; j < 8; ++j) M_b[base + j] = fmaxf(moff, wl[j]);
}

// ---------------- fused mLSTM attention (bf16 MFMA, swapped QK^T) ----------------
// grid (32, 8): block bx handles q-tiles {bx, 63-bx} (32 rows each) of head n.
// 4 waves: wave w -> q rows (w&1)*16, PV d-half (w>>1)*128. QK^T duplicated x2.
__global__ __launch_bounds__(256) void mlstm_attn(const ushort* __restrict__ qkv3,
    const float* __restrict__ e_b, const float* __restrict__ M_b,
    const float* __restrict__ wv_b, float* __restrict__ hflat) {
  const int n = blockIdx.y;
  const int bx = blockIdx.x;
  const int tid = threadIdx.x;
  const int w = tid >> 6, lane = tid & 63;
  const int g = lane >> 4, li = lane & 15;
  const int qr = (w & 1) * 16, dh2 = (w >> 1) * 128;

  __shared__ ushort Qs[32 * 256];
  __shared__ ushort Ks[32 * 256];
  __shared__ ushort Vt[256 * 36];
  __shared__ float wvs[32];
  __shared__ float scl[2][16];

  const int sr = tid >> 3;      // staging row 0..31
  const int sbb = tid & 7;

  for (int pass = 0; pass < 2; ++pass) {
    const int qt = pass ? (63 - bx) : bx;
    const int q0 = qt * 32;
    __syncthreads();
    // stage Q (scaled by 1/16), swizzled
    {
      const ushort* qsrc = qkv3 + (size_t)(q0 + sr) * 6144 + n * 256;
      char* qrow = (char*)Qs + sr * 512;
#pragma unroll
      for (int i = 0; i < 4; ++i) {
        const int b = sbb + 8 * i;
        uint4 u = *(const uint4*)(qsrc + b * 8);
        uint4 o;
        o.x = pk2(f2b(b2f((ushort)u.x) * 0.0625f), f2b(b2f((ushort)(u.x >> 16)) * 0.0625f));
        o.y = pk2(f2b(b2f((ushort)u.y) * 0.0625f), f2b(b2f((ushort)(u.y >> 16)) * 0.0625f));
        o.z = pk2(f2b(b2f((ushort)u.z) * 0.0625f), f2b(b2f((ushort)(u.z >> 16)) * 0.0625f));
        o.w = pk2(f2b(b2f((ushort)u.w) * 0.0625f), f2b(b2f((ushort)(u.w >> 16)) * 0.0625f));
        *(uint4*)(qrow + ((b ^ (sr & 7)) << 4)) = o;
      }
    }
    __syncthreads();

    bf16x8 qf[8];
#pragma unroll
    for (int dc = 0; dc < 8; ++dc) qf[dc] = frag_ld(Qs, 512, qr + li, dc * 64 + 8 * g);

    const int qg = q0 + qr + li;
    const float Mq = M_b[(size_t)n * L + qg];
    const float el = e_b[(size_t)n * L + qg];
    float rowsum = 0.f;
    f32x4 oacc[8];
#pragma unroll
    for (int db = 0; db < 8; ++db) oacc[db] = (f32x4){0.f, 0.f, 0.f, 0.f};

    const int nmt = qt + 1;
    for (int mt = 0; mt < nmt; ++mt) {
      const int m0 = mt * 32;
      __syncthreads();
      // stage K (swizzled) and V^T (padded stride 36)
      {
        const ushort* ksrc = qkv3 + (size_t)(m0 + sr) * 6144 + 2048 + n * 256;
        const ushort* vsrc = qkv3 + (size_t)(m0 + sr) * 6144 + 4096 + n * 256;
        char* krow = (char*)Ks + sr * 512;
#pragma unroll
        for (int i = 0; i < 4; ++i) {
          const int b = sbb + 8 * i;
          uint4 ku = *(const uint4*)(ksrc + b * 8);
          *(uint4*)(krow + ((b ^ (sr & 7)) << 4)) = ku;
          uint4 vu = *(const uint4*)(vsrc + b * 8);
          const int d0 = b * 8;
          ushort* vp = Vt + sr;
          vp[(d0 + 0) * 36] = (ushort)vu.x; vp[(d0 + 1) * 36] = (ushort)(vu.x >> 16);
          vp[(d0 + 2) * 36] = (ushort)vu.y; vp[(d0 + 3) * 36] = (ushort)(vu.y >> 16);
          vp[(d0 + 4) * 36] = (ushort)vu.z; vp[(d0 + 5) * 36] = (ushort)(vu.z >> 16);
          vp[(d0 + 6) * 36] = (ushort)vu.w; vp[(d0 + 7) * 36] = (ushort)(vu.w >> 16);
        }
        if (tid < 32) wvs[tid] = wv_b[(size_t)n * L + m0 + tid];
      }
      __syncthreads();

      // ST = K * Q^T  (two 16-row m halves)
      f32x4 st0 = (f32x4){0.f, 0.f, 0.f, 0.f}, st1 = (f32x4){0.f, 0.f, 0.f, 0.f};
#pragma unroll
      for (int dc = 0; dc < 8; ++dc) {
        bf16x8 kf0 = frag_ld(Ks, 512, li, dc * 64 + 8 * g);
        bf16x8 kf1 = frag_ld(Ks, 512, 16 + li, dc * 64 + 8 * g);
        st0 = __builtin_amdgcn_mfma_f32_16x16x32_bf16(kf0, qf[dc], st0, 0, 0, 0);
        st1 = __builtin_amdgcn_mfma_f32_16x16x32_bf16(kf1, qf[dc], st1, 0, 0, 0);
      }

      // P (weights + mask) stays in registers as the PV A-operand
      bf16x8 pa;
#pragma unroll
      for (int j = 0; j < 8; ++j) {
        const int h = j >> 2;
        const int mrel = 4 * g + (j & 3) + 16 * h;
        const float s = h ? st1[j & 3] : st0[j & 3];
        const int mg = m0 + mrel;
        float p = (mg <= qg) ? s * __expf(wvs[mrel] - Mq) : 0.f;
        rowsum += p;
        pa[j] = (short)f2b(p);
      }

      // O += P * V  (wave's 128-col d-half)
#pragma unroll
      for (int db = 0; db < 8; ++db) {
        const ushort* vb = Vt + (dh2 + db * 16 + li) * 36;
        bf16x8 vf;
        *(unsigned long long*)&vf = *(const unsigned long long*)(vb + 4 * g);
        *((unsigned long long*)&vf + 1) = *(const unsigned long long*)(vb + 4 * g + 16);
        oacc[db] = __builtin_amdgcn_mfma_f32_16x16x32_bf16(pa, vf, oacc[db], 0, 0, 0);
      }
    }

    // normalization
    rowsum += __shfl_xor(rowsum, 16);
    rowsum += __shfl_xor(rowsum, 32);
    const float sc = 1.f / (fmaxf(fabsf(rowsum), __expf(-(el + Mq))) + 1e-6f);
    if (w < 2 && lane < 16) scl[w][lane] = sc;
    __syncthreads();
    float scj[4];
#pragma unroll
    for (int j = 0; j < 4; ++j) scj[j] = scl[w & 1][4 * g + j];
#pragma unroll
    for (int db = 0; db < 8; ++db)
#pragma unroll
      for (int j = 0; j < 4; ++j)
        hflat[(size_t)(q0 + qr + 4 * g + j) * 2048 + n * 256 + dh2 + db * 16 + li] =
            oacc[db][j] * scj[j];
  }
}

// ---------------- GroupNorm + skip*xc, * silu(res) -> yb (bf16) ----------------
__global__ __launch_bounds__(64) void gn_y_kernel(const float* __restrict__ hflat,
    const ushort* __restrict__ xcb, const float* __restrict__ proj,
    const float* __restrict__ gnw, const float* __restrict__ gnb,
    const float* __restrict__ skip, ushort* __restrict__ yb) {
  const int n = blockIdx.x, l = blockIdx.y, lane = threadIdx.x;
  const float* hr = hflat + (size_t)l * DI + n * DHD;
  float vals[4]; float s = 0.f, s2 = 0.f;
#pragma unroll
  for (int u = 0; u < 4; ++u) {
    float t = hr[lane + u * 64]; vals[u] = t; s += t; s2 += t * t;
  }
#pragma unroll
  for (int off = 32; off; off >>= 1) { s += __shfl_xor(s, off); s2 += __shfl_xor(s2, off); }
  const float mean = s * (1.f / DHD);
  const float inv = rsqrtf(s2 * (1.f / DHD) - mean * mean + 1e-5f);
#pragma unroll
  for (int u = 0; u < 4; ++u) {
    const int c = n * DHD + lane + u * 64;
    const float hn = (vals[u] - mean) * inv;
    const float h2 = hn * gnw[c] + gnb[c] + skip[c] * b2f(xcb[(size_t)l * DI + c]);
    const float r = proj[(size_t)l * 4096 + 2048 + c];
    yb[(size_t)l * DI + c] = f2b(h2 * (r / (1.f + __expf(-r))));
  }
}

// ---------------- gelu(a) * z -> bf16 ----------------
__global__ __launch_bounds__(256) void gelu_mul_kernel(const float* __restrict__ p,
    ushort* __restrict__ gb) {
  const int idx = blockIdx.x * 256 + threadIdx.x;   // over L*512
  const int l = idx >> 9, c4 = (idx & 511) * 4;
  float4 a = *(const float4*)(p + (size_t)l * 4096 + c4);
  float4 z = *(const float4*)(p + (size_t)l * 4096 + 2048 + c4);
  float o[4];
  float av[4] = {a.x, a.y, a.z, a.w};
  float zv[4] = {z.x, z.y, z.z, z.w};
#pragma unroll
  for (int j = 0; j < 4; ++j) {
    const float t = 0.7978845608028654f * (av[j] + 0.044715f * av[j] * av[j] * av[j]);
    o[j] = 0.5f * av[j] * (1.f + tanhf(t)) * zv[j];
  }
  *(ushort4*)(gb + (size_t)l * 2048 + c4) =
      make_ushort4(f2b(o[0]), f2b(o[1]), f2b(o[2]), f2b(o[3]));
}

extern "C" void kernel_launch(void* const* d_in, const int* in_sizes, int n_in,
                              void* d_out, int out_size, void* d_ws, size_t ws_size,
                              hipStream_t stream) {
  const float* x     = (const float*)d_in[0];
  const float* ln1w  = (const float*)d_in[2];
  const float* winw  = (const float*)d_in[3];
  const float* winb  = (const float*)d_in[4];
  const float* woutw = (const float*)d_in[5];
  const float* ck    = (const float*)d_in[6];
  const float* cb    = (const float*)d_in[7];
  const float* wq    = (const float*)d_in[8];
  const float* wk    = (const float*)d_in[9];
  const float* wvw   = (const float*)d_in[10];
  const float* igw   = (const float*)d_in[11];
  const float* igb   = (const float*)d_in[12];
  const float* fgw   = (const float*)d_in[13];
  const float* fgb   = (const float*)d_in[14];
  const float* gnw   = (const float*)d_in[15];
  const float* gnb   = (const float*)d_in[16];
  const float* skip  = (const float*)d_in[17];
  const float* ln2w  = (const float*)d_in[18];
  const float* fwin  = (const float*)d_in[19];
  const float* fwout = (const float*)d_in[20];
  float* out = (float*)d_out;

  char* base = (char*)d_ws;
  const size_t MB = 1ull << 20;
  float*  proj  = (float*)(base);                 // 32 MiB  [f32; reused as p]
  float*  hflat = (float*)(base + 32 * MB);       // 16 MiB
  float*  x2    = (float*)(base + 48 * MB);       //  8 MiB
  float*  ig_t  = (float*)(base + 56 * MB);       // 5 x 64KB
  float*  fg_t  = ig_t + NH * L;
  float*  e_b   = fg_t + NH * L;
  float*  M_b   = e_b + NH * L;
  float*  wv_b  = M_b + NH * L;
  ushort* hb    = (ushort*)(base + 57 * MB);      //  4 MiB
  ushort* projb = (ushort*)(base + 61 * MB);      //  8 MiB (xi bf16; reused as yb, gb)
  ushort* xcb   = (ushort*)(base + 69 * MB);      //  8 MiB
  ushort* qkv3  = (ushort*)(base + 77 * MB);      // 24 MiB
  ushort* wA    = (ushort*)(base + 101 * MB);     //  8 MiB (win / fwin)
  ushort* wB    = (ushort*)(base + 109 * MB);     //  4 MiB (wout / fwout)
  ushort* wqkvT = (ushort*)(base + 113 * MB);     //  3 MiB
  ushort* gwB   = (ushort*)(base + 116 * MB);     //  0.2 MiB
  ushort* yb    = projb;
  ushort* gb    = projb;

  // weight preprocessing
  cast_kernel<<<2048, 256, 0, stream>>>(winw, wA, 4096 * 1024);
  cast_kernel<<<1024, 256, 0, stream>>>(woutw, wB, 1024 * 2048);
  wtrans_kernel<<<dim3(8, 8, 24), 256, 0, stream>>>(wq, wk, wvw, wqkvT);
  cast_kernel<<<24, 256, 0, stream>>>(igw, gwB, 8 * 6144);
  cast_kernel<<<24, 256, 0, stream>>>(fgw, gwB + 8 * 6144, 8 * 6144);

  // 1. hb = LN(x)
  ln_kernel<<<L, 256, 0, stream>>>(x, ln1w, hb, DM);
  // 2. proj = hb @ win^T + b  (f32 + bf16 copy of first 2048 cols)
  gemm_bf16<true, false, true, true><<<dim3(32, 16, 1), 256, 0, stream>>>(
      hb, 1024, 0, wA, 1024, 0, winb, nullptr, 0, proj, 4096, projb, 2048, 2048, 0, 1024);
  // 3. xcb = silu(conv(xi))
  conv_silu_kernel<<<(L * 512) / 256, 256, 0, stream>>>(proj, ck, cb, xcb);
  // 4. q,k,v head projections -> qkv3 [L][6144] bf16
  gemm_bf16<false, false, false, true><<<dim3(2, 16, 8), 256, 0, stream>>>(
      xcb, 2048, 256, wqkvT, 256, 65536, nullptr, nullptr, 0, nullptr, 0,
      qkv3, 6144, 1 << 30, 256, 256);
  gemm_bf16<false, false, false, true><<<dim3(2, 16, 8), 256, 0, stream>>>(
      xcb, 2048, 256, wqkvT + 8 * 65536, 256, 65536, nullptr, nullptr, 0, nullptr, 0,
      qkv3 + 2048, 6144, 1 << 30, 256, 256);
  gemm_bf16<false, false, false, true><<<dim3(2, 16, 8), 256, 0, stream>>>(
      projb, 2048, 256, wqkvT + 16 * 65536, 256, 65536, nullptr, nullptr, 0, nullptr, 0,
      qkv3 + 4096, 6144, 1 << 30, 256, 256);
  // 5. gates
  gates_kernel<<<L, 256, 0, stream>>>(qkv3, gwB, igb, fgb, ig_t, fg_t);
  // 6. scan
  scan_kernel<<<NH, 256, 0, stream>>>(ig_t, fg_t, e_b, M_b, wv_b);
  // 7. attention
  mlstm_attn<<<dim3(32, 8), 256, 0, stream>>>(qkv3, e_b, M_b, wv_b, hflat);
  // 8. yb = (GN(hflat) + skip*xc) * silu(res)
  gn_y_kernel<<<dim3(NH, L), 64, 0, stream>>>(hflat, xcb, proj, gnw, gnb, skip, yb);
  // 9. x2 = x + yb @ wout^T
  gemm_bf16<false, true, true, false><<<dim3(8, 16, 1), 256, 0, stream>>>(
      yb, 2048, 0, wB, 2048, 0, nullptr, x, 1024, x2, 1024, nullptr, 0, 0, 0, 2048);
  // 10. hb = LN(x2)
  ln_kernel<<<L, 256, 0, stream>>>(x2, ln2w, hb, DM);
  // ffn weight casts (reuse wA/wB)
  cast_kernel<<<2048, 256, 0, stream>>>(fwin, wA, 4096 * 1024);
  cast_kernel<<<1024, 256, 0, stream>>>(fwout, wB, 1024 * 2048);
  // 11. p = hb @ fwin^T   (reuse proj)
  gemm_bf16<false, false, true, false><<<dim3(32, 16, 1), 256, 0, stream>>>(
      hb, 1024, 0, wA, 1024, 0, nullptr, nullptr, 0, proj, 4096, nullptr, 0, 0, 0, 1024);
  // 12. gb = gelu(a) * z
  gelu_mul_kernel<<<(L * 512) / 256, 256, 0, stream>>>(proj, gb);
  // 13. out = x2 + gb @ fwout^T
  gemm_bf16<false, true, true, false><<<dim3(8, 16, 1), 256, 0, stream>>>(
      gb, 2048, 0, wB, 2048, 0, nullptr, x2, 1024, out, 1024, nullptr, 0, 0, 0, 2048);
}